// Round 3
// baseline (544.591 us; speedup 1.0000x reference)
//
#include <hip/hip_runtime.h>
#include <hip/hip_bf16.h>
#include <stdint.h>

#define B    4096
#define NU   20000
#define NI   10000
#define RS   10001   // interactions row stride (ints)
#define SPK  8       // split-K segments
#define GBS  625     // Gb row stride in dwords (20000 bits exactly)
#define XAS  320     // Xall/Xu row stride in dwords (10240 bits; 313 used)

typedef __attribute__((ext_vector_type(8))) short bf16x8;
typedef __attribute__((ext_vector_type(4))) float f32x4;

// ---------- P1: stream-pack all of X into bits (identity bit order) ----------
__global__ void k_packall(const int* __restrict__ X, unsigned long long* __restrict__ Xall) {
  int lane = threadIdx.x & 63, wv = threadIdx.x >> 6;
  for (int i = 0; i < 8; i++) {
    int u = blockIdx.x * 8 + i;
    const int* row = X + (size_t)u * RS;
    for (int w = wv; w < XAS / 2; w += 4) {
      int j = w * 64 + lane;
      int v = (j < NI) ? row[j] : 0;
      unsigned long long m = __ballot(v != 0);
      if (lane == 0) Xall[(size_t)u * (XAS / 2) + w] = m;
    }
  }
}

// ---------- P2: per-u gather of item columns from packed row: G[u][w] bit l = X[u][item_idx[w*64+l]] ----------
__global__ __launch_bounds__(256) void k_gatherG(const unsigned long long* __restrict__ Xall,
    const int* __restrict__ item_idx, unsigned long long* __restrict__ G) {
  __shared__ int sidx[B];
  __shared__ unsigned long long srow[XAS / 2];
  int u = blockIdx.x;
  for (int j = threadIdx.x; j < B; j += 256) sidx[j] = item_idx[j];
  for (int j = threadIdx.x; j < XAS / 2; j += 256) srow[j] = Xall[(size_t)u * (XAS / 2) + j];
  __syncthreads();
  int lane = threadIdx.x & 63, w = threadIdx.x >> 6;
  for (int wq = w; wq < 64; wq += 4) {
    int c = sidx[wq * 64 + lane];
    int bit = (int)((srow[c >> 6] >> (c & 63)) & 1ULL);
    unsigned long long m = __ballot(bit);
    if (lane == 0) G[(size_t)u * 64 + wq] = m;
  }
}

// ---------- P3: 64x64 bit-block transpose: G (u-major over b) -> Gb (b-major over u) ----------
__global__ void k_transG(const unsigned long long* __restrict__ G, uint32_t* __restrict__ Gb) {
  int lane = threadIdx.x & 63, w = threadIdx.x >> 6;
  int uc = blockIdx.x, wfull = blockIdx.y * 4 + w;
  int u = uc * 64 + lane;
  unsigned long long g = (u < NU) ? G[(size_t)u * 64 + wfull] : 0ULL;
  unsigned long long mym = 0;
#pragma unroll 8
  for (int j = 0; j < 64; j++) {
    unsigned long long mm = __ballot((int)((g >> j) & 1ULL));
    if (lane == j) mym = mm;
  }
  int b = wfull * 64 + lane;
  Gb[(size_t)b * GBS + uc * 2] = (uint32_t)mym;
  if (uc * 2 + 1 < GBS) Gb[(size_t)b * GBS + uc * 2 + 1] = (uint32_t)(mym >> 32);
}

// ---------- P4: gather packed user rows: Xu[b] = Xall[user_idx[b]] ----------
__global__ void k_packU(const unsigned long long* __restrict__ Xall,
    const int* __restrict__ user_idx, unsigned long long* __restrict__ Xu) {
  int wv = blockIdx.x * 4 + (threadIdx.x >> 6);
  int lane = threadIdx.x & 63;
  const unsigned long long* src = Xall + (size_t)user_idx[wv] * (XAS / 2);
  unsigned long long* dst = Xu + (size_t)wv * (XAS / 2);
  for (int j = lane; j < XAS / 2; j += 64) dst[j] = src[j];
}

// ---------- W: weight -> per-lane-contiguous bf16 fragment stream ----------
// slot (ks,t,lane,j): W[k = ks*32 + (lane>>4)*8 + j][f = t*16 + (lane&15)], src is (64 x NSRC) f32
__global__ void k_prepW(const float* __restrict__ src, int NSRC, int nk,
                        uint4* __restrict__ wfrag) {
  int idx = blockIdx.x * 256 + threadIdx.x;  // (ks*4 + t)*64 + l
  int l = idx & 63, t = (idx >> 6) & 3, ks = idx >> 8;
  if (ks >= nk) return;
  int g = l >> 4, f = t * 16 + (l & 15);
  int u0 = ks * 32 + g * 8;
  uint32_t w[4];
#pragma unroll
  for (int p = 0; p < 4; p++) {
    float lo = (u0 + 2 * p     < NSRC) ? src[(size_t)f * NSRC + u0 + 2 * p]     : 0.f;
    float hi = (u0 + 2 * p + 1 < NSRC) ? src[(size_t)f * NSRC + u0 + 2 * p + 1] : 0.f;
    __hip_bfloat16 blo = __float2bfloat16(lo), bhi = __float2bfloat16(hi);
    w[p] = (uint32_t)*(uint16_t*)&blo | ((uint32_t)*(uint16_t*)&bhi << 16);
  }
  wfrag[idx] = make_uint4(w[0], w[1], w[2], w[3]);
}

// ---------- M: MFMA GEMM: partF[seg][b][f] = sum_{k in seg} bit(b,k) * W[k][f] ----------
__global__ __launch_bounds__(256) void k_mfma(const uint32_t* __restrict__ bits, int bstride,
    const uint4* __restrict__ wfrag, int nk, float* __restrict__ partF) {
  int lane = threadIdx.x & 63, wid = threadIdx.x >> 6;
  int mtile = blockIdx.x * 4 + wid, seg = blockIdx.y;
  int b0 = mtile * 16;
  int row = b0 + (lane & 15), g = lane >> 4;
  f32x4 acc[4] = {{0,0,0,0},{0,0,0,0},{0,0,0,0},{0,0,0,0}};
  const uint32_t* brow = bits + (size_t)row * bstride;
  for (int ks = seg; ks < nk; ks += SPK) {
    uint32_t ab = brow[ks];
    uint32_t by = (ab >> (g * 8)) & 0xffu;
    union { bf16x8 v; uint32_t u[4]; } A;
#pragma unroll
    for (int p = 0; p < 4; p++) {
      uint32_t blo = (by >> (2 * p)) & 1u, bhi = (by >> (2 * p + 1)) & 1u;
      A.u[p] = (blo ? 0x3F80u : 0u) | (bhi ? 0x3F800000u : 0u);
    }
    const uint4* wp = wfrag + (size_t)ks * 256 + lane;
#pragma unroll
    for (int t = 0; t < 4; t++) {
      union { bf16x8 v; uint4 q; } Bf;
      Bf.q = wp[t * 64];
      acc[t] = __builtin_amdgcn_mfma_f32_16x16x32_bf16(A.v, Bf.v, acc[t], 0, 0, 0);
    }
  }
#pragma unroll
  for (int t = 0; t < 4; t++)
#pragma unroll
    for (int r = 0; r < 4; r++) {
      int b = b0 + (lane >> 4) * 4 + r;
      partF[((size_t)seg * B + b) * 64 + t * 16 + (lane & 15)] = acc[t][r];
    }
}

// ---------- R: reduce split-K + popcount + mask-fix + normalize + embed add ----------
// mode 0 (user): mask row = item_idx[b] in src, embed row = user_idx[b]
// mode 1 (item): mask row = user_idx[b] in src, embed row = item_idx[b]
__global__ void k_reduceB(const float* __restrict__ partF,
    const uint32_t* __restrict__ bits, int bstride, int ndw,
    const int* __restrict__ user_idx, const int* __restrict__ item_idx,
    const int* __restrict__ X, const float* __restrict__ src, int NSRC,
    const float* __restrict__ embed, int mode, float* __restrict__ rep) {
  int gid = blockIdx.x * 256 + threadIdx.x;
  int b = gid >> 6, f = gid & 63;
  float a = 0.f;
  for (int s = 0; s < SPK; s++) a += partF[((size_t)s * B + b) * 64 + f];
  const uint32_t* rowp = bits + (size_t)b * bstride;
  int c = 0;
  for (int d = f; d < ndw; d += 64) c += __popc(rowp[d]);
  for (int off = 32; off; off >>= 1) c += __shfl_xor(c, off);
  int u = user_idx[b], it = item_idx[b];
  int xc = X[(size_t)u * RS + it];
  int mrow = mode ? u : it;
  if (xc) { a -= src[(size_t)f * NSRC + mrow]; c -= 1; }
  float denom = (float)c;
  if (denom < 1.f) denom = 1.f;
  int erow = mode ? it : u;
  rep[(size_t)b * 64 + f] = embed[(size_t)erow * 64 + f] + a / sqrtf(denom);
}

// ---------- L: GMF dot + bias ----------
__global__ void k_logit(const float* __restrict__ ru, const float* __restrict__ ri,
    const float* __restrict__ lw, const float* __restrict__ lb, float* __restrict__ out) {
  int lane = threadIdx.x & 63, w = threadIdx.x >> 6;
  int b = blockIdx.x * 4 + w;
  float v = ru[(size_t)b * 64 + lane] * ri[(size_t)b * 64 + lane] * lw[lane];
  for (int off = 32; off; off >>= 1) v += __shfl_xor(v, off);
  if (lane == 0) out[b] = v + lb[0];
}

extern "C" void kernel_launch(void* const* d_in, const int* in_sizes, int n_in,
                              void* d_out, int out_size, void* d_ws, size_t ws_size,
                              hipStream_t stream) {
  const int*   user_idx = (const int*)d_in[0];
  const int*   item_idx = (const int*)d_in[1];
  const int*   X        = (const int*)d_in[2];
  const float* uew      = (const float*)d_in[3];
  const float* iew      = (const float*)d_in[4];
  const float* pu       = (const float*)d_in[5];   // (64, 10000)
  const float* pi       = (const float*)d_in[6];   // (64, 20000)
  const float* lw       = (const float*)d_in[7];
  const float* lb       = (const float*)d_in[8];
  float* out = (float*)d_out;

  char* wsb = (char*)d_ws;
  unsigned long long* Xall  = (unsigned long long*)(wsb + 0);         // 25,600,000 B
  unsigned long long* G     = (unsigned long long*)(wsb + 25600000);  // 10,240,000 B
  uint32_t*           Gb    = (uint32_t*)(wsb + 35840000);            // 10,240,000 B
  unsigned long long* Xu    = (unsigned long long*)(wsb + 46080000);  //  5,242,880 B
  uint4*              WfI   = (uint4*)(wsb + 51322880);               //  2,560,000 B
  uint4*              WfU   = (uint4*)(wsb + 53882880);               //  1,282,048 B
  float*              partF = (float*)(wsb + 55164928);               //  8,388,608 B
  float*              rep_u = (float*)(wsb + 63553536);               //  1,048,576 B
  float*              rep_i = (float*)(wsb + 64602112);               //  1,048,576 B

  k_prepW<<<625, 256, 0, stream>>>(pi, NU, 625, WfI);
  k_prepW<<<313, 256, 0, stream>>>(pu, NI, 313, WfU);
  k_packall<<<2500, 256, 0, stream>>>(X, Xall);
  k_gatherG<<<NU, 256, 0, stream>>>(Xall, item_idx, G);
  k_transG<<<dim3(313, 16), 256, 0, stream>>>(G, Gb);
  k_packU<<<1024, 256, 0, stream>>>(Xall, user_idx, Xu);

  // item path: hist_i[b][f] = sum_u Gb(b,u) * pi[f][u]
  k_mfma<<<dim3(64, SPK), 256, 0, stream>>>(Gb, GBS, WfI, 625, partF);
  k_reduceB<<<1024, 256, 0, stream>>>(partF, Gb, GBS, 625,
      user_idx, item_idx, X, pi, NU, iew, 1, rep_i);

  // user path: hist_u[b][f] = sum_j Xu(b,j) * pu[f][j]
  k_mfma<<<dim3(64, SPK), 256, 0, stream>>>((const uint32_t*)Xu, XAS, WfU, 313, partF);
  k_reduceB<<<1024, 256, 0, stream>>>(partF, (const uint32_t*)Xu, XAS, 313,
      user_idx, item_idx, X, pu, NI, uew, 0, rep_u);

  k_logit<<<1024, 256, 0, stream>>>(rep_u, rep_i, lw, lb, out);
}

// Round 4
// 405.596 us; speedup vs baseline: 1.3427x; 1.3427x over previous
//
#include <hip/hip_runtime.h>
#include <hip/hip_bf16.h>
#include <stdint.h>

#define B    4096
#define NU   20000
#define NI   10000
#define RS   10001   // interactions row stride (ints)
#define SPK  16      // split-K segments
#define XAS  320     // Xall/Xu row stride in dwords (10240 bits; 313 used)
#define XTS  640     // XallT/Gbi row stride in dwords (20480 bits; 625 used)
#define NKI  625     // item K dwords (20000 bits)
#define NKU  313     // user K dwords (10000+16 pad bits)
#define KCHI 40      // ceil(625/16)
#define KCHU 20      // ceil(313/16)

typedef __attribute__((ext_vector_type(8))) short bf16x8;
typedef __attribute__((ext_vector_type(4))) float f32x4;

// ---------- P1: stream-pack all of X into bits (identity bit order) ----------
__global__ void k_packall(const int* __restrict__ X, unsigned long long* __restrict__ Xall) {
  int lane = threadIdx.x & 63, wv = threadIdx.x >> 6;
  int u = blockIdx.x;
  const int* row = X + (size_t)u * RS;
  unsigned long long* dst = Xall + (size_t)u * (XAS / 2);
  for (int w = wv; w < XAS / 2; w += 4) {
    int j = w * 64 + lane;
    int v = (j < NI) ? row[j] : 0;
    unsigned long long m = __ballot(v != 0);
    if (lane == 0) dst[w] = m;
  }
}

// ---------- P2: full bit transpose: Xall (u-major over j) -> XallT (j-major over u) ----------
// tile: 64 j's (word w) x 512 u's (band of 8 uc). lane l owns row j=w*64+l, writes 64 B.
__global__ __launch_bounds__(256) void k_bitT(const unsigned long long* __restrict__ Xall,
                                              uint32_t* __restrict__ XallT) {
  int lane = threadIdx.x & 63, wid = threadIdx.x >> 6;
  int w = blockIdx.x * 4 + wid;
  int band = blockIdx.y;
  if (w >= 157) return;
  unsigned long long g[8];
#pragma unroll
  for (int c = 0; c < 8; c++) {
    int u = (band * 8 + c) * 64 + lane;
    g[c] = (u < NU) ? Xall[(size_t)u * (XAS / 2) + w] : 0ULL;
  }
  union { unsigned long long o[8]; uint4 q[4]; } T;
#pragma unroll
  for (int c = 0; c < 8; c++) {
    unsigned long long mym = 0;
#pragma unroll
    for (int jj = 0; jj < 64; jj++) {
      unsigned long long m = __ballot((int)((g[c] >> jj) & 1ULL));
      if (lane == jj) mym = m;
    }
    T.o[c] = mym;
  }
  int j = w * 64 + lane;
  uint4* dst = (uint4*)(XallT + (size_t)j * XTS + band * 16);
#pragma unroll
  for (int q = 0; q < 4; q++) dst[q] = T.q[q];
}

// ---------- P3: packed-row gather (uint4 rows) ----------
__global__ void k_rowgather(const uint4* __restrict__ src, const int* __restrict__ idx,
                            uint4* __restrict__ dst, int n16) {
  int wid = threadIdx.x >> 6, lane = threadIdx.x & 63;
  int b = blockIdx.x * 4 + wid;
  const uint4* s = src + (size_t)idx[b] * n16;
  uint4* d = dst + (size_t)b * n16;
  for (int j = lane; j < n16; j += 64) d[j] = s[j];
}

// ---------- W: weight -> per-lane-contiguous bf16 fragment stream ----------
// slot (ks,t,lane,j): W[k = ks*32 + (lane>>4)*8 + j][f = t*16 + (lane&15)], src is (64 x NSRC) f32
__global__ void k_prepW(const float* __restrict__ src, int NSRC, int nk,
                        uint4* __restrict__ wfrag) {
  int idx = blockIdx.x * 256 + threadIdx.x;
  int l = idx & 63, t = (idx >> 6) & 3, ks = idx >> 8;
  if (ks >= nk) return;
  int g = l >> 4, f = t * 16 + (l & 15);
  int u0 = ks * 32 + g * 8;
  uint32_t w[4];
#pragma unroll
  for (int p = 0; p < 4; p++) {
    float lo = (u0 + 2 * p     < NSRC) ? src[(size_t)f * NSRC + u0 + 2 * p]     : 0.f;
    float hi = (u0 + 2 * p + 1 < NSRC) ? src[(size_t)f * NSRC + u0 + 2 * p + 1] : 0.f;
    __hip_bfloat16 blo = __float2bfloat16(lo), bhi = __float2bfloat16(hi);
    w[p] = (uint32_t)*(uint16_t*)&blo | ((uint32_t)*(uint16_t*)&bhi << 16);
  }
  wfrag[idx] = make_uint4(w[0], w[1], w[2], w[3]);
}

// ---------- M: MFMA GEMM, contiguous split-K, LDS double-buffered B stream ----------
__global__ __launch_bounds__(256) void k_mfma(const uint32_t* __restrict__ bits, int bstride,
    const uint4* __restrict__ wfrag, int nk, int kch, float* __restrict__ partF) {
  __shared__ uint4 wt[2][256];
  int tid = threadIdx.x;
  int lane = tid & 63, wid = tid >> 6;
  int mtile = blockIdx.x * 4 + wid, seg = blockIdx.y;
  int b0 = mtile * 16;
  int row = b0 + (lane & 15), g = lane >> 4;
  int kbeg = seg * kch;
  int kend = min(nk, kbeg + kch);
  f32x4 acc[4] = {{0,0,0,0},{0,0,0,0},{0,0,0,0},{0,0,0,0}};
  const uint32_t* brow = bits + (size_t)row * bstride;
  wt[0][tid] = wfrag[(size_t)kbeg * 256 + tid];
  __syncthreads();
  int i = 0;
  for (int ks = kbeg; ks < kend; ++ks, ++i) {
    int cur = i & 1;
    uint4 vn;
    bool hasnext = (ks + 1 < kend);
    if (hasnext) vn = wfrag[(size_t)(ks + 1) * 256 + tid];
    uint32_t ab = brow[ks];
    uint32_t by = (ab >> (g * 8)) & 0xffu;
    union { bf16x8 v; uint32_t u[4]; } A;
#pragma unroll
    for (int p = 0; p < 4; p++) {
      uint32_t blo = (by >> (2 * p)) & 1u, bhi = (by >> (2 * p + 1)) & 1u;
      A.u[p] = (blo ? 0x3F80u : 0u) | (bhi ? 0x3F800000u : 0u);
    }
#pragma unroll
    for (int t = 0; t < 4; t++) {
      union { bf16x8 v; uint4 q; } Bf;
      Bf.q = wt[cur][t * 64 + lane];
      acc[t] = __builtin_amdgcn_mfma_f32_16x16x32_bf16(A.v, Bf.v, acc[t], 0, 0, 0);
    }
    if (hasnext) wt[cur ^ 1][tid] = vn;
    __syncthreads();
  }
#pragma unroll
  for (int t = 0; t < 4; t++)
#pragma unroll
    for (int r = 0; r < 4; r++) {
      int b = b0 + (lane >> 4) * 4 + r;
      partF[((size_t)seg * B + b) * 64 + t * 16 + (lane & 15)] = acc[t][r];
    }
}

// ---------- R: reduce split-K + popcount + mask-fix + normalize + embed add ----------
__global__ void k_reduceB(const float* __restrict__ partF,
    const uint32_t* __restrict__ bits, int bstride, int ndw,
    const int* __restrict__ user_idx, const int* __restrict__ item_idx,
    const int* __restrict__ X, const float* __restrict__ src, int NSRC,
    const float* __restrict__ embed, int mode, float* __restrict__ rep) {
  int gid = blockIdx.x * 256 + threadIdx.x;
  int b = gid >> 6, f = gid & 63;
  float a = 0.f;
  for (int s = 0; s < SPK; s++) a += partF[((size_t)s * B + b) * 64 + f];
  const uint32_t* rowp = bits + (size_t)b * bstride;
  int c = 0;
  for (int d = f; d < ndw; d += 64) c += __popc(rowp[d]);
  for (int off = 32; off; off >>= 1) c += __shfl_xor(c, off);
  int u = user_idx[b], it = item_idx[b];
  int xc = X[(size_t)u * RS + it];
  int mrow = mode ? u : it;
  if (xc) { a -= src[(size_t)f * NSRC + mrow]; c -= 1; }
  float denom = (float)c;
  if (denom < 1.f) denom = 1.f;
  int erow = mode ? it : u;
  rep[(size_t)b * 64 + f] = embed[(size_t)erow * 64 + f] + a / sqrtf(denom);
}

// ---------- L: GMF dot + bias ----------
__global__ void k_logit(const float* __restrict__ ru, const float* __restrict__ ri,
    const float* __restrict__ lw, const float* __restrict__ lb, float* __restrict__ out) {
  int lane = threadIdx.x & 63, w = threadIdx.x >> 6;
  int b = blockIdx.x * 4 + w;
  float v = ru[(size_t)b * 64 + lane] * ri[(size_t)b * 64 + lane] * lw[lane];
  for (int off = 32; off; off >>= 1) v += __shfl_xor(v, off);
  if (lane == 0) out[b] = v + lb[0];
}

extern "C" void kernel_launch(void* const* d_in, const int* in_sizes, int n_in,
                              void* d_out, int out_size, void* d_ws, size_t ws_size,
                              hipStream_t stream) {
  const int*   user_idx = (const int*)d_in[0];
  const int*   item_idx = (const int*)d_in[1];
  const int*   X        = (const int*)d_in[2];
  const float* uew      = (const float*)d_in[3];
  const float* iew      = (const float*)d_in[4];
  const float* pu       = (const float*)d_in[5];   // (64, 10000)
  const float* pi       = (const float*)d_in[6];   // (64, 20000)
  const float* lw       = (const float*)d_in[7];
  const float* lb       = (const float*)d_in[8];
  float* out = (float*)d_out;

  char* wsb = (char*)d_ws;
  unsigned long long* Xall  = (unsigned long long*)(wsb + 0);         // 25,600,000
  uint32_t*           XallT = (uint32_t*)(wsb + 25600000);            // 25,722,880 (10048 x 2560B)
  unsigned long long* Xu    = (unsigned long long*)(wsb + 51322880);  //  5,242,880
  uint32_t*           Gbi   = (uint32_t*)(wsb + 56565760);            // 10,485,760
  uint4*              WfI   = (uint4*)(wsb + 67051520);               //  2,560,000
  uint4*              WfU   = (uint4*)(wsb + 69611520);               //  1,282,048
  float*              partF = (float*)(wsb + 70893568);               // 16,777,216
  float*              rep_u = (float*)(wsb + 87670784);               //  1,048,576
  float*              rep_i = (float*)(wsb + 88719360);               //  1,048,576

  k_prepW<<<NKI, 256, 0, stream>>>(pi, NU, NKI, WfI);
  k_prepW<<<NKU, 256, 0, stream>>>(pu, NI, NKU, WfU);
  k_packall<<<NU, 256, 0, stream>>>(X, Xall);
  k_bitT<<<dim3(40, 40), 256, 0, stream>>>(Xall, XallT);
  k_rowgather<<<1024, 256, 0, stream>>>((const uint4*)Xall,  user_idx, (uint4*)Xu,  XAS / 4);
  k_rowgather<<<1024, 256, 0, stream>>>((const uint4*)XallT, item_idx, (uint4*)Gbi, XTS / 4);

  // item path: hist_i[b][f] = sum_u Gbi(b,u) * pi[f][u]
  k_mfma<<<dim3(64, SPK), 256, 0, stream>>>(Gbi, XTS, WfI, NKI, KCHI, partF);
  k_reduceB<<<1024, 256, 0, stream>>>(partF, Gbi, XTS, NKI,
      user_idx, item_idx, X, pi, NU, iew, 1, rep_i);

  // user path: hist_u[b][f] = sum_j Xu(b,j) * pu[f][j]
  k_mfma<<<dim3(64, SPK), 256, 0, stream>>>((const uint32_t*)Xu, XAS, WfU, NKU, KCHU, partF);
  k_reduceB<<<1024, 256, 0, stream>>>(partF, (const uint32_t*)Xu, XAS, NKU,
      user_idx, item_idx, X, pu, NI, uew, 0, rep_u);

  k_logit<<<1024, 256, 0, stream>>>(rep_u, rep_i, lw, lb, out);
}

// Round 5
// 374.287 us; speedup vs baseline: 1.4550x; 1.0836x over previous
//
#include <hip/hip_runtime.h>
#include <hip/hip_bf16.h>
#include <stdint.h>

#define B    4096
#define NU   20000
#define NI   10000
#define RS   10001   // interactions row stride (ints)
#define SPK  16      // split-K segments
#define XAS  320     // Xall row stride in dwords (10240 bits; 10000 used)
#define XTS  640     // XallT row stride in dwords (20480 bits; 20000 used)
#define NKI  625     // item K dwords (20000 bits)
#define NKU  313     // user K dwords (10000+16 pad bits)
#define KCHI 40      // ceil(625/16)
#define KCHU 20      // ceil(313/16)

typedef __attribute__((ext_vector_type(8))) short bf16x8;
typedef __attribute__((ext_vector_type(4))) float f32x4;

// ---------- P1: stream-pack all of X into bits (identity bit order), MLP=8 ----------
__global__ __launch_bounds__(256) void k_packall(const int* __restrict__ X,
                                                 uint32_t* __restrict__ Xall) {
  int lane = threadIdx.x & 63, wv = threadIdx.x >> 6;
  int u = blockIdx.x;
  const int* row = X + (size_t)u * RS;
  uint32_t* dst = Xall + (size_t)u * XAS;
  for (int gq = wv; gq < 20; gq += 4) {          // 20 groups x 512 columns
    int j0 = gq * 512;
    int v[8];
#pragma unroll
    for (int s = 0; s < 8; s++) {
      int j = j0 + s * 64 + lane;
      v[s] = (j < NI) ? row[j] : 0;
    }
    unsigned long long m[8];
#pragma unroll
    for (int s = 0; s < 8; s++) m[s] = __ballot(v[s] != 0);
    if (lane < 4) {
      // lane L packs words 2L, 2L+1 (all m's are wave-uniform; static select tree)
      unsigned long long a = (lane & 2) ? ((lane & 1) ? m[6] : m[4])
                                        : ((lane & 1) ? m[2] : m[0]);
      unsigned long long c = (lane & 2) ? ((lane & 1) ? m[7] : m[5])
                                        : ((lane & 1) ? m[3] : m[1]);
      uint4 val;
      val.x = (uint32_t)a; val.y = (uint32_t)(a >> 32);
      val.z = (uint32_t)c; val.w = (uint32_t)(c >> 32);
      ((uint4*)(dst + gq * 16))[lane] = val;
    }
  }
}

// ---------- P2: full bit transpose: Xall (u-major over j) -> XallT (j-major over u) ----------
__global__ __launch_bounds__(256) void k_bitT(const unsigned long long* __restrict__ Xall,
                                              uint32_t* __restrict__ XallT) {
  int lane = threadIdx.x & 63, wid = threadIdx.x >> 6;
  int w = blockIdx.x * 4 + wid;
  int band = blockIdx.y;
  if (w >= 157) return;
  unsigned long long g[8];
#pragma unroll
  for (int c = 0; c < 8; c++) {
    int u = (band * 8 + c) * 64 + lane;
    g[c] = (u < NU) ? Xall[(size_t)u * (XAS / 2) + w] : 0ULL;
  }
  union { unsigned long long o[8]; uint4 q[4]; } T;
#pragma unroll
  for (int c = 0; c < 8; c++) {
    unsigned long long mym = 0;
#pragma unroll
    for (int jj = 0; jj < 64; jj++) {
      unsigned long long m = __ballot((int)((g[c] >> jj) & 1ULL));
      if (lane == jj) mym = m;
    }
    T.o[c] = mym;
  }
  int j = w * 64 + lane;
  uint4* dst = (uint4*)(XallT + (size_t)j * XTS + band * 16);
#pragma unroll
  for (int q = 0; q < 4; q++) dst[q] = T.q[q];
}

// ---------- W: weight -> per-lane-contiguous bf16 fragment stream (LDS-staged) ----------
// wfrag[ks*256 + t*64 + l].w[p] = pack(W[ks*32+(l>>4)*8+2p][f], W[..+2p+1][f]), f=t*16+(l&15)
__global__ __launch_bounds__(256) void k_prepW(const float* __restrict__ src, int NSRC,
                                               uint4* __restrict__ wfrag) {
  __shared__ float tile[64][33];
  int ks = blockIdx.x;
  int tid = threadIdx.x;
  {
    int f = tid >> 2, part = tid & 3;
    int ubase = ks * 32 + part * 8;
    const float* sp = src + (size_t)f * NSRC;
#pragma unroll
    for (int q = 0; q < 8; q++) {
      int u = ubase + q;
      tile[f][part * 8 + q] = (u < NSRC) ? sp[u] : 0.f;
    }
  }
  __syncthreads();
  int l = tid & 63, t = tid >> 6;
  int g = l >> 4, f = t * 16 + (l & 15);
  int u0 = g * 8;
  uint32_t w[4];
#pragma unroll
  for (int p = 0; p < 4; p++) {
    __hip_bfloat16 blo = __float2bfloat16(tile[f][u0 + 2 * p]);
    __hip_bfloat16 bhi = __float2bfloat16(tile[f][u0 + 2 * p + 1]);
    w[p] = (uint32_t)*(uint16_t*)&blo | ((uint32_t)*(uint16_t*)&bhi << 16);
  }
  wfrag[(size_t)ks * 256 + tid] = make_uint4(w[0], w[1], w[2], w[3]);
}

// ---------- M: MFMA GEMM over indexed bit rows, LDS-dbuf B stream ----------
__global__ __launch_bounds__(256) void k_mfma(const uint32_t* __restrict__ bits, int bstride,
    const int* __restrict__ idx, const uint4* __restrict__ wfrag, int nk, int kch,
    float* __restrict__ partF) {
  __shared__ uint4 wt[2][256];
  int tid = threadIdx.x;
  int lane = tid & 63, wid = tid >> 6;
  int mtile = blockIdx.x * 4 + wid, seg = blockIdx.y;
  int b0 = mtile * 16;
  int row = b0 + (lane & 15), g = lane >> 4;
  int kbeg = seg * kch;
  int kend = min(nk, kbeg + kch);
  f32x4 acc[4] = {{0,0,0,0},{0,0,0,0},{0,0,0,0},{0,0,0,0}};
  const uint32_t* brow = bits + (size_t)idx[row] * bstride;
  wt[0][tid] = wfrag[(size_t)kbeg * 256 + tid];
  __syncthreads();
  int i = 0;
  for (int ks = kbeg; ks < kend; ++ks, ++i) {
    int cur = i & 1;
    uint4 vn;
    bool hasnext = (ks + 1 < kend);
    if (hasnext) vn = wfrag[(size_t)(ks + 1) * 256 + tid];
    uint32_t ab = brow[ks];
    uint32_t by = (ab >> (g * 8)) & 0xffu;
    union { bf16x8 v; uint32_t u[4]; } A;
#pragma unroll
    for (int p = 0; p < 4; p++) {
      uint32_t blo = (by >> (2 * p)) & 1u, bhi = (by >> (2 * p + 1)) & 1u;
      A.u[p] = (blo ? 0x3F80u : 0u) | (bhi ? 0x3F800000u : 0u);
    }
#pragma unroll
    for (int t = 0; t < 4; t++) {
      union { bf16x8 v; uint4 q; } Bf;
      Bf.q = wt[cur][t * 64 + lane];
      acc[t] = __builtin_amdgcn_mfma_f32_16x16x32_bf16(A.v, Bf.v, acc[t], 0, 0, 0);
    }
    if (hasnext) wt[cur ^ 1][tid] = vn;
    __syncthreads();
  }
#pragma unroll
  for (int t = 0; t < 4; t++)
#pragma unroll
    for (int r = 0; r < 4; r++) {
      int b = b0 + (lane >> 4) * 4 + r;
      partF[((size_t)seg * B + b) * 64 + t * 16 + (lane & 15)] = acc[t][r];
    }
}

// ---------- R: reduce split-K + popcount(indexed row) + mask-fix + normalize + embed ----------
__global__ void k_reduceB(const float* __restrict__ partF,
    const uint32_t* __restrict__ bits, int bstride, int ndw,
    const int* __restrict__ rowidx,
    const int* __restrict__ user_idx, const int* __restrict__ item_idx,
    const int* __restrict__ X, const float* __restrict__ src, int NSRC,
    const float* __restrict__ embed, int mode, float* __restrict__ rep) {
  int gid = blockIdx.x * 256 + threadIdx.x;
  int b = gid >> 6, f = gid & 63;
  float a = 0.f;
  for (int s = 0; s < SPK; s++) a += partF[((size_t)s * B + b) * 64 + f];
  const uint32_t* rowp = bits + (size_t)rowidx[b] * bstride;
  int c = 0;
  for (int d = f; d < ndw; d += 64) c += __popc(rowp[d]);
  for (int off = 32; off; off >>= 1) c += __shfl_xor(c, off);
  int u = user_idx[b], it = item_idx[b];
  int xc = X[(size_t)u * RS + it];
  int mrow = mode ? u : it;
  if (xc) { a -= src[(size_t)f * NSRC + mrow]; c -= 1; }
  float denom = (float)c;
  if (denom < 1.f) denom = 1.f;
  int erow = mode ? it : u;
  rep[(size_t)b * 64 + f] = embed[(size_t)erow * 64 + f] + a / sqrtf(denom);
}

// ---------- L: GMF dot + bias ----------
__global__ void k_logit(const float* __restrict__ ru, const float* __restrict__ ri,
    const float* __restrict__ lw, const float* __restrict__ lb, float* __restrict__ out) {
  int lane = threadIdx.x & 63, w = threadIdx.x >> 6;
  int b = blockIdx.x * 4 + w;
  float v = ru[(size_t)b * 64 + lane] * ri[(size_t)b * 64 + lane] * lw[lane];
  for (int off = 32; off; off >>= 1) v += __shfl_xor(v, off);
  if (lane == 0) out[b] = v + lb[0];
}

extern "C" void kernel_launch(void* const* d_in, const int* in_sizes, int n_in,
                              void* d_out, int out_size, void* d_ws, size_t ws_size,
                              hipStream_t stream) {
  const int*   user_idx = (const int*)d_in[0];
  const int*   item_idx = (const int*)d_in[1];
  const int*   X        = (const int*)d_in[2];
  const float* uew      = (const float*)d_in[3];
  const float* iew      = (const float*)d_in[4];
  const float* pu       = (const float*)d_in[5];   // (64, 10000)
  const float* pi       = (const float*)d_in[6];   // (64, 20000)
  const float* lw       = (const float*)d_in[7];
  const float* lb       = (const float*)d_in[8];
  float* out = (float*)d_out;

  char* wsb = (char*)d_ws;
  uint32_t* Xall  = (uint32_t*)(wsb + 0);            // 25,600,000
  uint32_t* XallT = (uint32_t*)(wsb + 25600000);     // 25,722,880 (10048 x 2560B)
  uint4*    WfI   = (uint4*)(wsb + 51322880);        //  2,560,000
  uint4*    WfU   = (uint4*)(wsb + 53882880);        //  1,282,048
  float*    partF = (float*)(wsb + 55164928);        // 16,777,216
  float*    rep_u = (float*)(wsb + 71942144);        //  1,048,576
  float*    rep_i = (float*)(wsb + 72990720);        //  1,048,576

  k_prepW<<<NKI, 256, 0, stream>>>(pi, NU, WfI);
  k_prepW<<<NKU, 256, 0, stream>>>(pu, NI, WfU);
  k_packall<<<NU, 256, 0, stream>>>(X, Xall);
  k_bitT<<<dim3(40, 40), 256, 0, stream>>>((const unsigned long long*)Xall, XallT);

  // item path: hist_i[b][f] = sum_u bit(XallT[item_idx[b]], u) * pi[f][u]
  k_mfma<<<dim3(64, SPK), 256, 0, stream>>>(XallT, XTS, item_idx, WfI, NKI, KCHI, partF);
  k_reduceB<<<1024, 256, 0, stream>>>(partF, XallT, XTS, NKI, item_idx,
      user_idx, item_idx, X, pi, NU, iew, 1, rep_i);

  // user path: hist_u[b][f] = sum_j bit(Xall[user_idx[b]], j) * pu[f][j]
  k_mfma<<<dim3(64, SPK), 256, 0, stream>>>(Xall, XAS, user_idx, WfU, NKU, KCHU, partF);
  k_reduceB<<<1024, 256, 0, stream>>>(partF, Xall, XAS, NKU, user_idx,
      user_idx, item_idx, X, pu, NI, uew, 0, rep_u);

  k_logit<<<1024, 256, 0, stream>>>(rep_u, rep_i, lw, lb, out);
}

// Round 6
// 373.281 us; speedup vs baseline: 1.4589x; 1.0027x over previous
//
#include <hip/hip_runtime.h>
#include <hip/hip_bf16.h>
#include <stdint.h>

#define B    4096
#define NU   20000
#define NI   10000
#define RS   10001   // interactions row stride (ints)
#define XAS  320     // Xall row stride in dwords (10240 bits; 10000 used)
#define XTS  640     // XallT row stride in dwords (20480 bits; 20000 used)
#define NKI  625     // item K dwords (20000 bits)
#define NKU  313     // user K dwords (10000+16 pad bits)
#define SPI  32      // item split-K segments (kch 20)
#define SPU  16      // user split-K segments (kch 20)
#define KCH  20

typedef __attribute__((ext_vector_type(8))) short bf16x8;
typedef __attribute__((ext_vector_type(4))) float f32x4;

// ---------- P1: stream-pack all of X into bits (identity bit order), MLP=8 ----------
__global__ __launch_bounds__(256) void k_packall(const int* __restrict__ X,
                                                 uint32_t* __restrict__ Xall) {
  int lane = threadIdx.x & 63, wv = threadIdx.x >> 6;
  int u = blockIdx.x;
  const int* row = X + (size_t)u * RS;
  uint32_t* dst = Xall + (size_t)u * XAS;
  for (int gq = wv; gq < 20; gq += 4) {          // 20 groups x 512 columns
    int j0 = gq * 512;
    int v[8];
#pragma unroll
    for (int s = 0; s < 8; s++) {
      int j = j0 + s * 64 + lane;
      v[s] = (j < NI) ? row[j] : 0;
    }
    unsigned long long m[8];
#pragma unroll
    for (int s = 0; s < 8; s++) m[s] = __ballot(v[s] != 0);
    if (lane < 4) {
      unsigned long long a = (lane & 2) ? ((lane & 1) ? m[6] : m[4])
                                        : ((lane & 1) ? m[2] : m[0]);
      unsigned long long c = (lane & 2) ? ((lane & 1) ? m[7] : m[5])
                                        : ((lane & 1) ? m[3] : m[1]);
      uint4 val;
      val.x = (uint32_t)a; val.y = (uint32_t)(a >> 32);
      val.z = (uint32_t)c; val.w = (uint32_t)(c >> 32);
      ((uint4*)(dst + gq * 16))[lane] = val;
    }
  }
}

// ---------- P2: full bit transpose: Xall (u-major over j) -> XallT (j-major over u) ----------
__global__ __launch_bounds__(256) void k_bitT(const unsigned long long* __restrict__ Xall,
                                              uint32_t* __restrict__ XallT) {
  int lane = threadIdx.x & 63, wid = threadIdx.x >> 6;
  int w = blockIdx.x * 4 + wid;
  int band = blockIdx.y;
  if (w >= 157) return;
  unsigned long long g[8];
#pragma unroll
  for (int c = 0; c < 8; c++) {
    int u = (band * 8 + c) * 64 + lane;
    g[c] = (u < NU) ? Xall[(size_t)u * (XAS / 2) + w] : 0ULL;
  }
  union { unsigned long long o[8]; uint4 q[4]; } T;
#pragma unroll
  for (int c = 0; c < 8; c++) {
    unsigned long long mym = 0;
#pragma unroll
    for (int jj = 0; jj < 64; jj++) {
      unsigned long long m = __ballot((int)((g[c] >> jj) & 1ULL));
      if (lane == jj) mym = m;
    }
    T.o[c] = mym;
  }
  int j = w * 64 + lane;
  uint4* dst = (uint4*)(XallT + (size_t)j * XTS + band * 16);
#pragma unroll
  for (int q = 0; q < 4; q++) dst[q] = T.q[q];
}

// ---------- W: both weights -> per-lane-contiguous bf16 fragment streams (one launch) ----------
// wfrag[ks*256 + t*64 + l].w[p] = pack(W[ks*32+(l>>4)*8+2p][f], W[..+2p+1][f]), f=t*16+(l&15)
__global__ __launch_bounds__(256) void k_prepW2(const float* __restrict__ pi,
    const float* __restrict__ pu, uint4* __restrict__ WfI, uint4* __restrict__ WfU) {
  __shared__ float tile[64][33];
  const float* src; uint4* wfrag; int NSRC, ks;
  if (blockIdx.x < NKI) { src = pi; wfrag = WfI; NSRC = NU; ks = blockIdx.x; }
  else                  { src = pu; wfrag = WfU; NSRC = NI; ks = blockIdx.x - NKI; }
  int tid = threadIdx.x;
  {
    int f = tid >> 2, part = tid & 3;
    int ubase = ks * 32 + part * 8;
    const float* sp = src + (size_t)f * NSRC;
#pragma unroll
    for (int q = 0; q < 8; q++) {
      int u = ubase + q;
      tile[f][part * 8 + q] = (u < NSRC) ? sp[u] : 0.f;
    }
  }
  __syncthreads();
  int l = tid & 63, t = tid >> 6;
  int g = l >> 4, f = t * 16 + (l & 15);
  int u0 = g * 8;
  uint32_t w[4];
#pragma unroll
  for (int p = 0; p < 4; p++) {
    __hip_bfloat16 blo = __float2bfloat16(tile[f][u0 + 2 * p]);
    __hip_bfloat16 bhi = __float2bfloat16(tile[f][u0 + 2 * p + 1]);
    w[p] = (uint32_t)*(uint16_t*)&blo | ((uint32_t)*(uint16_t*)&bhi << 16);
  }
  wfrag[(size_t)ks * 256 + tid] = make_uint4(w[0], w[1], w[2], w[3]);
}

// ---------- M: barrierless MFMA GEMM, M=32 rows/wave, item+user in one launch ----------
__global__ __launch_bounds__(256) void k_mfma2(
    const uint32_t* __restrict__ XallT, const uint32_t* __restrict__ Xall,
    const uint4* __restrict__ WfI, const uint4* __restrict__ WfU,
    const int* __restrict__ item_idx, const int* __restrict__ user_idx,
    float* __restrict__ partFI, float* __restrict__ partFU) {
  int lane = threadIdx.x & 63, wid = threadIdx.x >> 6;
  const uint32_t* bits; const uint4* wf; float* pf; const int* idx;
  int bstride, nk, seg, pair;
  if (blockIdx.x < 1024) {               // item: 32 pairs x 32 segs
    pair = blockIdx.x & 31; seg = blockIdx.x >> 5;
    bits = XallT; bstride = XTS; wf = WfI; pf = partFI; idx = item_idx; nk = NKI;
  } else {                               // user: 32 pairs x 16 segs
    int bx = blockIdx.x - 1024;
    pair = bx & 31; seg = bx >> 5;
    bits = Xall; bstride = XAS; wf = WfU; pf = partFU; idx = user_idx; nk = NKU;
  }
  int b0 = pair * 128 + wid * 32;
  int r0 = b0 + (lane & 15);
  int g = lane >> 4;
  int kbeg = seg * KCH, kend = min(nk, kbeg + KCH);
  const uint32_t* brow0 = bits + (size_t)idx[r0] * bstride;
  const uint32_t* brow1 = bits + (size_t)idx[r0 + 16] * bstride;
  f32x4 acc0[4] = {{0,0,0,0},{0,0,0,0},{0,0,0,0},{0,0,0,0}};
  f32x4 acc1[4] = {{0,0,0,0},{0,0,0,0},{0,0,0,0},{0,0,0,0}};
  for (int ks = kbeg; ks < kend; ++ks) {
    uint32_t by0 = (brow0[ks] >> (g * 8)) & 0xffu;
    uint32_t by1 = (brow1[ks] >> (g * 8)) & 0xffu;
    union { bf16x8 v; uint32_t u[4]; } A0, A1;
#pragma unroll
    for (int p = 0; p < 4; p++) {
      A0.u[p] = (((by0 >> (2 * p)) & 1u) ? 0x3F80u : 0u) |
                (((by0 >> (2 * p + 1)) & 1u) ? 0x3F800000u : 0u);
      A1.u[p] = (((by1 >> (2 * p)) & 1u) ? 0x3F80u : 0u) |
                (((by1 >> (2 * p + 1)) & 1u) ? 0x3F800000u : 0u);
    }
    const uint4* wp = wf + (size_t)ks * 256 + lane;
#pragma unroll
    for (int t = 0; t < 4; t++) {
      union { bf16x8 v; uint4 q; } Bf;
      Bf.q = wp[t * 64];
      acc0[t] = __builtin_amdgcn_mfma_f32_16x16x32_bf16(A0.v, Bf.v, acc0[t], 0, 0, 0);
      acc1[t] = __builtin_amdgcn_mfma_f32_16x16x32_bf16(A1.v, Bf.v, acc1[t], 0, 0, 0);
    }
  }
#pragma unroll
  for (int t = 0; t < 4; t++)
#pragma unroll
    for (int r = 0; r < 4; r++) {
      int b = b0 + (lane >> 4) * 4 + r;
      int f = t * 16 + (lane & 15);
      pf[((size_t)seg * B + b) * 64 + f] = acc0[t][r];
      pf[((size_t)seg * B + (b + 16)) * 64 + f] = acc1[t][r];
    }
}

// ---------- F: fused split-K reduce (both paths) + popcount + mask-fix + normalize
//             + embed add + GMF dot + bias ----------
__global__ __launch_bounds__(256) void k_final(
    const float* __restrict__ partFI, const float* __restrict__ partFU,
    const uint32_t* __restrict__ XallT, const uint32_t* __restrict__ Xall,
    const int* __restrict__ user_idx, const int* __restrict__ item_idx,
    const int* __restrict__ X, const float* __restrict__ pi, const float* __restrict__ pu,
    const float* __restrict__ uew, const float* __restrict__ iew,
    const float* __restrict__ lw, const float* __restrict__ lb,
    float* __restrict__ out) {
  int gid = blockIdx.x * 256 + threadIdx.x;
  int b = gid >> 6, f = gid & 63;
  int u = user_idx[b], it = item_idx[b];
  float ai = 0.f, au = 0.f;
  for (int s = 0; s < SPI; s++) ai += partFI[((size_t)s * B + b) * 64 + f];
  for (int s = 0; s < SPU; s++) au += partFU[((size_t)s * B + b) * 64 + f];
  const uint32_t* rowi = XallT + (size_t)it * XTS;
  const uint32_t* rowu = Xall + (size_t)u * XAS;
  int ci = 0, cu = 0;
  for (int d = f; d < NKI; d += 64) ci += __popc(rowi[d]);
  for (int d = f; d < NKU; d += 64) cu += __popc(rowu[d]);
  for (int off = 32; off; off >>= 1) {
    ci += __shfl_xor(ci, off);
    cu += __shfl_xor(cu, off);
  }
  int xc = X[(size_t)u * RS + it];
  if (xc) {
    ai -= pi[(size_t)f * NU + u];  ci -= 1;
    au -= pu[(size_t)f * NI + it]; cu -= 1;
  }
  float di = (float)ci; if (di < 1.f) di = 1.f;
  float du = (float)cu; if (du < 1.f) du = 1.f;
  float repi = iew[(size_t)it * 64 + f] + ai / sqrtf(di);
  float repu = uew[(size_t)u * 64 + f] + au / sqrtf(du);
  float v = repu * repi * lw[f];
  for (int off = 32; off; off >>= 1) v += __shfl_xor(v, off);
  if ((threadIdx.x & 63) == 0) out[b] = v + lb[0];
}

extern "C" void kernel_launch(void* const* d_in, const int* in_sizes, int n_in,
                              void* d_out, int out_size, void* d_ws, size_t ws_size,
                              hipStream_t stream) {
  const int*   user_idx = (const int*)d_in[0];
  const int*   item_idx = (const int*)d_in[1];
  const int*   X        = (const int*)d_in[2];
  const float* uew      = (const float*)d_in[3];
  const float* iew      = (const float*)d_in[4];
  const float* pu       = (const float*)d_in[5];   // (64, 10000)
  const float* pi       = (const float*)d_in[6];   // (64, 20000)
  const float* lw       = (const float*)d_in[7];
  const float* lb       = (const float*)d_in[8];
  float* out = (float*)d_out;

  char* wsb = (char*)d_ws;
  uint32_t* Xall   = (uint32_t*)(wsb + 0);             // 25,600,000
  uint32_t* XallT  = (uint32_t*)(wsb + 25600000);      // 25,722,880 (10048 x 2560B)
  uint4*    WfI    = (uint4*)(wsb + 51322880);         //  2,560,000
  uint4*    WfU    = (uint4*)(wsb + 53882880);         //  1,282,048
  float*    partFI = (float*)(wsb + 55164928);         // 33,554,432
  float*    partFU = (float*)(wsb + 88719360);         // 16,777,216

  k_prepW2<<<NKI + NKU, 256, 0, stream>>>(pi, pu, WfI, WfU);
  k_packall<<<NU, 256, 0, stream>>>(X, Xall);
  k_bitT<<<dim3(40, 40), 256, 0, stream>>>((const unsigned long long*)Xall, XallT);
  k_mfma2<<<1536, 256, 0, stream>>>(XallT, Xall, WfI, WfU, item_idx, user_idx,
                                    partFI, partFU);
  k_final<<<1024, 256, 0, stream>>>(partFI, partFU, XallT, Xall,
                                    user_idx, item_idx, X, pi, pu, uew, iew, lw, lb, out);
}

// Round 7
// 332.030 us; speedup vs baseline: 1.6402x; 1.1242x over previous
//
#include <hip/hip_runtime.h>
#include <hip/hip_bf16.h>
#include <stdint.h>

#define B    4096
#define NU   20000
#define NI   10000
#define RS   10001   // interactions row stride (ints)
#define XAS  320     // Xall row stride in dwords (10240 bits; 10000 used)
#define XTS  640     // XallT row stride in dwords (20480 bits; 20000 used)
#define NKI  625     // item K dwords (20000 bits)
#define NKU  313     // user K dwords (10000+16 pad bits)
#define SPI  32      // item split-K segments (kch 20)
#define SPU  16      // user split-K segments (kch 20)
#define KCH  20

typedef __attribute__((ext_vector_type(8))) short bf16x8;
typedef __attribute__((ext_vector_type(4))) float f32x4;

// ---------- P1: stream-pack X into bits, 16B/lane loads, one wave per row ----------
// Row base dword D0 = u*10001 has phase m=u&3; vector body starts at column
// h=(4-m)&3 so all uint4 loads are 16B-aligned. Body word k (cols h+32k..h+32k+31)
// is funnel-shifted into output word stream: out[k] = (W_k << h) | (W_{k-1} >> (32-h)).
__global__ __launch_bounds__(256) void k_packall(const int* __restrict__ X,
                                                 uint32_t* __restrict__ Xall) {
  int lane = threadIdx.x & 63, wv = threadIdx.x >> 6;
  int u = blockIdx.x * 4 + wv;
  const uint32_t* row = (const uint32_t*)(X + (size_t)u * RS);
  uint32_t* dst = Xall + (size_t)u * XAS;
  int h = (4 - (u & 3)) & 3;
  if (lane < 7) dst[313 + lane] = 0;                 // pad words for bitT's u64 reads
  // W_{-1}: head cols 0..h-1 placed at top bits
  uint32_t mh = (uint32_t)__ballot(lane < h && row[lane] != 0);
  uint32_t carry = h ? (mh << (32 - h)) : 0u;
  for (int it = 0; it < 40; ++it) {
    int c0 = h + it * 256 + lane * 4;                // this lane's first column
    uint4 v;
    if (c0 + 3 < NI) {
      v = *(const uint4*)(row + c0);                 // 16B-aligned by construction
    } else {
      uint32_t t0 = (c0     < NI) ? row[c0]     : 0u;
      uint32_t t1 = (c0 + 1 < NI) ? row[c0 + 1] : 0u;
      uint32_t t2 = (c0 + 2 < NI) ? row[c0 + 2] : 0u;
      uint32_t t3 = (c0 + 3 < NI) ? row[c0 + 3] : 0u;
      v = make_uint4(t0, t1, t2, t3);
    }
    uint32_t nib = (v.x ? 1u : 0u) | (v.y ? 2u : 0u) | (v.z ? 4u : 0u) | (v.w ? 8u : 0u);
    uint32_t acc = nib << ((lane & 7) * 4);
    acc |= __shfl_xor(acc, 1);
    acc |= __shfl_xor(acc, 2);
    acc |= __shfl_xor(acc, 4);                       // acc = body word it*8 + lane/8
    uint32_t prev = __shfl_up(acc, 8);
    if (lane < 8) prev = carry;
    uint32_t nextcarry = __shfl(acc, 63);
    uint32_t outw = h ? ((acc << h) | (prev >> (32 - h))) : acc;
    int k = it * 8 + (lane >> 3);
    if ((lane & 7) == 0 && k < 313) dst[k] = outw;
    carry = nextcarry;
  }
}

// ---------- P2: full bit transpose: Xall (u-major over j) -> XallT (j-major over u) ----------
__global__ __launch_bounds__(256) void k_bitT(const unsigned long long* __restrict__ Xall,
                                              uint32_t* __restrict__ XallT) {
  int lane = threadIdx.x & 63, wid = threadIdx.x >> 6;
  int w = blockIdx.x * 4 + wid;
  int band = blockIdx.y;
  if (w >= 157) return;
  unsigned long long g[8];
#pragma unroll
  for (int c = 0; c < 8; c++) {
    int u = (band * 8 + c) * 64 + lane;
    g[c] = (u < NU) ? Xall[(size_t)u * (XAS / 2) + w] : 0ULL;
  }
  union { unsigned long long o[8]; uint4 q[4]; } T;
#pragma unroll
  for (int c = 0; c < 8; c++) {
    unsigned long long mym = 0;
#pragma unroll
    for (int jj = 0; jj < 64; jj++) {
      unsigned long long m = __ballot((int)((g[c] >> jj) & 1ULL));
      if (lane == jj) mym = m;
    }
    T.o[c] = mym;
  }
  int j = w * 64 + lane;
  uint4* dst = (uint4*)(XallT + (size_t)j * XTS + band * 16);
#pragma unroll
  for (int q = 0; q < 4; q++) dst[q] = T.q[q];
}

// ---------- W: both weights -> per-lane-contiguous bf16 fragment streams (one launch) ----------
__global__ __launch_bounds__(256) void k_prepW2(const float* __restrict__ pi,
    const float* __restrict__ pu, uint4* __restrict__ WfI, uint4* __restrict__ WfU) {
  __shared__ float tile[64][33];
  const float* src; uint4* wfrag; int NSRC, ks;
  if (blockIdx.x < NKI) { src = pi; wfrag = WfI; NSRC = NU; ks = blockIdx.x; }
  else                  { src = pu; wfrag = WfU; NSRC = NI; ks = blockIdx.x - NKI; }
  int tid = threadIdx.x;
  {
    int f = tid >> 2, part = tid & 3;
    int ubase = ks * 32 + part * 8;
    const float* sp = src + (size_t)f * NSRC;
#pragma unroll
    for (int q = 0; q < 8; q++) {
      int u = ubase + q;
      tile[f][part * 8 + q] = (u < NSRC) ? sp[u] : 0.f;
    }
  }
  __syncthreads();
  int l = tid & 63, t = tid >> 6;
  int g = l >> 4, f = t * 16 + (l & 15);
  int u0 = g * 8;
  uint32_t w[4];
#pragma unroll
  for (int p = 0; p < 4; p++) {
    __hip_bfloat16 blo = __float2bfloat16(tile[f][u0 + 2 * p]);
    __hip_bfloat16 bhi = __float2bfloat16(tile[f][u0 + 2 * p + 1]);
    w[p] = (uint32_t)*(uint16_t*)&blo | ((uint32_t)*(uint16_t*)&bhi << 16);
  }
  wfrag[(size_t)ks * 256 + tid] = make_uint4(w[0], w[1], w[2], w[3]);
}

// ---------- M: barrierless MFMA GEMM, M=32 rows/wave, item+user in one launch ----------
__global__ __launch_bounds__(256) void k_mfma2(
    const uint32_t* __restrict__ XallT, const uint32_t* __restrict__ Xall,
    const uint4* __restrict__ WfI, const uint4* __restrict__ WfU,
    const int* __restrict__ item_idx, const int* __restrict__ user_idx,
    float* __restrict__ partFI, float* __restrict__ partFU) {
  int lane = threadIdx.x & 63, wid = threadIdx.x >> 6;
  const uint32_t* bits; const uint4* wf; float* pf; const int* idx;
  int bstride, nk, seg, pair;
  if (blockIdx.x < 1024) {               // item: 32 pairs x 32 segs
    pair = blockIdx.x & 31; seg = blockIdx.x >> 5;
    bits = XallT; bstride = XTS; wf = WfI; pf = partFI; idx = item_idx; nk = NKI;
  } else {                               // user: 32 pairs x 16 segs
    int bx = blockIdx.x - 1024;
    pair = bx & 31; seg = bx >> 5;
    bits = Xall; bstride = XAS; wf = WfU; pf = partFU; idx = user_idx; nk = NKU;
  }
  int b0 = pair * 128 + wid * 32;
  int r0 = b0 + (lane & 15);
  int g = lane >> 4;
  int kbeg = seg * KCH, kend = min(nk, kbeg + KCH);
  const uint32_t* brow0 = bits + (size_t)idx[r0] * bstride;
  const uint32_t* brow1 = bits + (size_t)idx[r0 + 16] * bstride;
  f32x4 acc0[4] = {{0,0,0,0},{0,0,0,0},{0,0,0,0},{0,0,0,0}};
  f32x4 acc1[4] = {{0,0,0,0},{0,0,0,0},{0,0,0,0},{0,0,0,0}};
  for (int ks = kbeg; ks < kend; ++ks) {
    uint32_t by0 = (brow0[ks] >> (g * 8)) & 0xffu;
    uint32_t by1 = (brow1[ks] >> (g * 8)) & 0xffu;
    union { bf16x8 v; uint32_t u[4]; } A0, A1;
#pragma unroll
    for (int p = 0; p < 4; p++) {
      A0.u[p] = (((by0 >> (2 * p)) & 1u) ? 0x3F80u : 0u) |
                (((by0 >> (2 * p + 1)) & 1u) ? 0x3F800000u : 0u);
      A1.u[p] = (((by1 >> (2 * p)) & 1u) ? 0x3F80u : 0u) |
                (((by1 >> (2 * p + 1)) & 1u) ? 0x3F800000u : 0u);
    }
    const uint4* wp = wf + (size_t)ks * 256 + lane;
#pragma unroll
    for (int t = 0; t < 4; t++) {
      union { bf16x8 v; uint4 q; } Bf;
      Bf.q = wp[t * 64];
      acc0[t] = __builtin_amdgcn_mfma_f32_16x16x32_bf16(A0.v, Bf.v, acc0[t], 0, 0, 0);
      acc1[t] = __builtin_amdgcn_mfma_f32_16x16x32_bf16(A1.v, Bf.v, acc1[t], 0, 0, 0);
    }
  }
#pragma unroll
  for (int t = 0; t < 4; t++)
#pragma unroll
    for (int r = 0; r < 4; r++) {
      int b = b0 + (lane >> 4) * 4 + r;
      int f = t * 16 + (lane & 15);
      pf[((size_t)seg * B + b) * 64 + f] = acc0[t][r];
      pf[((size_t)seg * B + (b + 16)) * 64 + f] = acc1[t][r];
    }
}

// ---------- F: fused split-K reduce (both paths) + popcount + mask-fix + normalize
//             + embed add + GMF dot + bias ----------
__global__ __launch_bounds__(256) void k_final(
    const float* __restrict__ partFI, const float* __restrict__ partFU,
    const uint32_t* __restrict__ XallT, const uint32_t* __restrict__ Xall,
    const int* __restrict__ user_idx, const int* __restrict__ item_idx,
    const int* __restrict__ X, const float* __restrict__ pi, const float* __restrict__ pu,
    const float* __restrict__ uew, const float* __restrict__ iew,
    const float* __restrict__ lw, const float* __restrict__ lb,
    float* __restrict__ out) {
  int gid = blockIdx.x * 256 + threadIdx.x;
  int b = gid >> 6, f = gid & 63;
  int u = user_idx[b], it = item_idx[b];
  float ai = 0.f, au = 0.f;
  for (int s = 0; s < SPI; s++) ai += partFI[((size_t)s * B + b) * 64 + f];
  for (int s = 0; s < SPU; s++) au += partFU[((size_t)s * B + b) * 64 + f];
  const uint32_t* rowi = XallT + (size_t)it * XTS;
  const uint32_t* rowu = Xall + (size_t)u * XAS;
  int ci = 0, cu = 0;
  for (int d = f; d < NKI; d += 64) ci += __popc(rowi[d]);
  for (int d = f; d < NKU; d += 64) cu += __popc(rowu[d]);
  for (int off = 32; off; off >>= 1) {
    ci += __shfl_xor(ci, off);
    cu += __shfl_xor(cu, off);
  }
  int xc = X[(size_t)u * RS + it];
  if (xc) {
    ai -= pi[(size_t)f * NU + u];  ci -= 1;
    au -= pu[(size_t)f * NI + it]; cu -= 1;
  }
  float di = (float)ci; if (di < 1.f) di = 1.f;
  float du = (float)cu; if (du < 1.f) du = 1.f;
  float repi = iew[(size_t)it * 64 + f] + ai / sqrtf(di);
  float repu = uew[(size_t)u * 64 + f] + au / sqrtf(du);
  float v = repu * repi * lw[f];
  for (int off = 32; off; off >>= 1) v += __shfl_xor(v, off);
  if ((threadIdx.x & 63) == 0) out[b] = v + lb[0];
}

extern "C" void kernel_launch(void* const* d_in, const int* in_sizes, int n_in,
                              void* d_out, int out_size, void* d_ws, size_t ws_size,
                              hipStream_t stream) {
  const int*   user_idx = (const int*)d_in[0];
  const int*   item_idx = (const int*)d_in[1];
  const int*   X        = (const int*)d_in[2];
  const float* uew      = (const float*)d_in[3];
  const float* iew      = (const float*)d_in[4];
  const float* pu       = (const float*)d_in[5];   // (64, 10000)
  const float* pi       = (const float*)d_in[6];   // (64, 20000)
  const float* lw       = (const float*)d_in[7];
  const float* lb       = (const float*)d_in[8];
  float* out = (float*)d_out;

  char* wsb = (char*)d_ws;
  uint32_t* Xall   = (uint32_t*)(wsb + 0);             // 25,600,000
  uint32_t* XallT  = (uint32_t*)(wsb + 25600000);      // 25,722,880 (10048 x 2560B)
  uint4*    WfI    = (uint4*)(wsb + 51322880);         //  2,560,000
  uint4*    WfU    = (uint4*)(wsb + 53882880);         //  1,282,048
  float*    partFI = (float*)(wsb + 55164928);         // 33,554,432
  float*    partFU = (float*)(wsb + 88719360);         // 16,777,216

  k_prepW2<<<NKI + NKU, 256, 0, stream>>>(pi, pu, WfI, WfU);
  k_packall<<<5000, 256, 0, stream>>>(X, Xall);
  k_bitT<<<dim3(40, 40), 256, 0, stream>>>((const unsigned long long*)Xall, XallT);
  k_mfma2<<<1536, 256, 0, stream>>>(XallT, Xall, WfI, WfU, item_idx, user_idx,
                                    partFI, partFU);
  k_final<<<1024, 256, 0, stream>>>(partFI, partFU, XallT, Xall,
                                    user_idx, item_idx, X, pi, pu, uew, iew, lw, lb, out);
}